// Round 10
// baseline (284.413 us; speedup 1.0000x reference)
//
#include <hip/hip_runtime.h>
#include <hip/hip_cooperative_groups.h>
#include <math.h>

namespace cg = cooperative_groups;

#define NPV 3072
#define LDP 3073
#define EPSF 1e-8f
#define NMOM 52            // [0..6] w-moments, [7..51] 45-entry sym tensor
#define NSEG 64
#define SEGROWS (NPV / NSEG)   // 48
#define NTILE_ROW 768      // row-groups (4 rows each)
#define NTILE_COL 768      // col tiles (seg = g/12, chunk = g%12)
#define NTILE_MRG 192      // merge tiles (16 cols each)
#define NTILE_MOM 12       // moment tiles (256 rows each)
#define NPART 48           // moment partials (NTILE_MOM * 4 waves)

#define INS3(v, a, b, c) do { \
    float _m1 = fminf((a), (v)); (a) = fmaxf((a), (v)); \
    float _m2 = fminf((b), _m1); (b) = fmaxf((b), _m1); \
    (c) = fmaxf((c), _m2); } while (0)

#define MRG3(x, y, z, a, b, c) do { \
    INS3((x), a, b, c); INS3((y), a, b, c); INS3((z), a, b, c); } while (0)

__device__ __forceinline__ void kinv6(const float* __restrict__ Kmat,
        float& ki0, float& ki1, float& ki2, float& ki3, float& ki4, float& ki5)
{
    float k00 = Kmat[0], k01 = Kmat[1], k02 = Kmat[2];
    float k10 = Kmat[3], k11 = Kmat[4], k12 = Kmat[5];
    float k20 = Kmat[6], k21 = Kmat[7], k22 = Kmat[8];
    float det = k00 * (k11 * k22 - k12 * k21) - k01 * (k10 * k22 - k12 * k20) + k02 * (k10 * k21 - k11 * k20);
    float id = 1.0f / det;
    ki0 = (k11 * k22 - k12 * k21) * id; ki1 = (k02 * k21 - k01 * k22) * id; ki2 = (k01 * k12 - k02 * k11) * id;
    ki3 = (k12 * k20 - k10 * k22) * id; ki4 = (k00 * k22 - k02 * k20) * id; ki5 = (k02 * k10 - k00 * k12) * id;
}

// ---------------- Phase 1: row top-3 (one wave per row, 4 rows/tile) --------
__device__ __forceinline__ void ph_rowtop3(const float* __restrict__ P,
        float* __restrict__ tr, int* __restrict__ rowcnt, int g, int t)
{
    int lane = t & 63;
    int i = g * 4 + (t >> 6);
    const float* row = P + (size_t)i * LDP;
    float a0 = -1e30f, b0 = -1e30f, c0 = -1e30f;
    float a1 = -1e30f, b1 = -1e30f, c1 = -1e30f;
    float a2 = -1e30f, b2 = -1e30f, c2 = -1e30f;
    float a3 = -1e30f, b3 = -1e30f, c3 = -1e30f;
    #pragma unroll
    for (int r = 0; r < 48; r += 4) {
        float v0 = row[(r + 0) * 64 + lane];
        float v1 = row[(r + 1) * 64 + lane];
        float v2 = row[(r + 2) * 64 + lane];
        float v3 = row[(r + 3) * 64 + lane];
        INS3(v0, a0, b0, c0);
        INS3(v1, a1, b1, c1);
        INS3(v2, a2, b2, c2);
        INS3(v3, a3, b3, c3);
    }
    MRG3(a1, b1, c1, a0, b0, c0);
    MRG3(a2, b2, c2, a0, b0, c0);
    MRG3(a3, b3, c3, a0, b0, c0);
    #pragma unroll
    for (int off = 1; off < 64; off <<= 1) {
        float xa = __shfl_xor(a0, off);
        float xb = __shfl_xor(b0, off);
        float xc = __shfl_xor(c0, off);
        MRG3(xa, xb, xc, a0, b0, c0);
    }
    if (lane == 0) { tr[i] = c0; rowcnt[i] = 0; }
}

// ---------------- Phase 2: col top-3 partials + candidate append ------------
__device__ __forceinline__ void cand(float v, int i, int j, const float* __restrict__ tr,
        int* __restrict__ rowcnt, int* __restrict__ rowj, float* __restrict__ roww)
{
    if (v >= tr[i] && v > 0.01f) {
        int s = atomicAdd(&rowcnt[i], 1);
        if (s < 8) { rowj[(size_t)i * 8 + s] = j; roww[(size_t)i * 8 + s] = v; }
    }
}

__device__ __forceinline__ void ph_col(const float* __restrict__ P,
        const float* __restrict__ tr, float4* __restrict__ part,
        int* __restrict__ rowcnt, int* __restrict__ rowj, float* __restrict__ roww,
        int g, int t)
{
    int j = (g % 12) * 256 + t;
    int i0 = (g / 12) * SEGROWS;
    float a0 = -1e30f, b0 = -1e30f, c0 = -1e30f;
    float a1 = -1e30f, b1 = -1e30f, c1 = -1e30f;
    float a2 = -1e30f, b2 = -1e30f, c2 = -1e30f;
    float a3 = -1e30f, b3 = -1e30f, c3 = -1e30f;
    float a4 = -1e30f, b4 = -1e30f, c4 = -1e30f;
    float a5 = -1e30f, b5 = -1e30f, c5 = -1e30f;
    float a6 = -1e30f, b6 = -1e30f, c6 = -1e30f;
    float a7 = -1e30f, b7 = -1e30f, c7 = -1e30f;
    #pragma unroll
    for (int r = 0; r < SEGROWS; r += 8) {
        int i = i0 + r;
        const float* col = P + (size_t)i * LDP + j;
        float v0 = col[0 * LDP];
        float v1 = col[1 * LDP];
        float v2 = col[2 * LDP];
        float v3 = col[3 * LDP];
        float v4 = col[4 * LDP];
        float v5 = col[5 * LDP];
        float v6 = col[6 * LDP];
        float v7 = col[7 * LDP];
        INS3(v0, a0, b0, c0);
        INS3(v1, a1, b1, c1);
        INS3(v2, a2, b2, c2);
        INS3(v3, a3, b3, c3);
        INS3(v4, a4, b4, c4);
        INS3(v5, a5, b5, c5);
        INS3(v6, a6, b6, c6);
        INS3(v7, a7, b7, c7);
        cand(v0, i + 0, j, tr, rowcnt, rowj, roww);
        cand(v1, i + 1, j, tr, rowcnt, rowj, roww);
        cand(v2, i + 2, j, tr, rowcnt, rowj, roww);
        cand(v3, i + 3, j, tr, rowcnt, rowj, roww);
        cand(v4, i + 4, j, tr, rowcnt, rowj, roww);
        cand(v5, i + 5, j, tr, rowcnt, rowj, roww);
        cand(v6, i + 6, j, tr, rowcnt, rowj, roww);
        cand(v7, i + 7, j, tr, rowcnt, rowj, roww);
    }
    MRG3(a1, b1, c1, a0, b0, c0);
    MRG3(a2, b2, c2, a0, b0, c0);
    MRG3(a3, b3, c3, a0, b0, c0);
    MRG3(a4, b4, c4, a0, b0, c0);
    MRG3(a5, b5, c5, a0, b0, c0);
    MRG3(a6, b6, c6, a0, b0, c0);
    MRG3(a7, b7, c7, a0, b0, c0);
    part[(size_t)(g / 12) * NPV + j] = make_float4(a0, b0, c0, 0.f);
}

// ---------------- Phase 3: merge col partials -> tc -------------------------
__device__ __forceinline__ void ph_merge(const float4* __restrict__ part,
        float* __restrict__ tc, int g, int t)
{
    int sub = t & 15;
    int j = g * 16 + (t >> 4);
    float4 buf[NSEG / 16];
    #pragma unroll
    for (int k = 0; k < NSEG / 16; ++k)
        buf[k] = part[(size_t)(sub + (k << 4)) * NPV + j];
    float a = -1e30f, b = -1e30f, c = -1e30f;
    #pragma unroll
    for (int k = 0; k < NSEG / 16; ++k) MRG3(buf[k].x, buf[k].y, buf[k].z, a, b, c);
    #pragma unroll
    for (int off = 1; off < 16; off <<= 1) {
        float xa = __shfl_xor(a, off);
        float xb = __shfl_xor(b, off);
        float xc = __shfl_xor(c, off);
        MRG3(xa, xb, xc, a, b, c);
    }
    if (sub == 0) tc[j] = c;
}

// ---------------- Phase 4: raw moments (one thread per row) -----------------
__device__ __forceinline__ void acc_pair(float* m, float w, float xs1, float ys1,
                                         float xs2, float ys2)
{
    m[0] += w;
    m[1] += w * xs1; m[2] += w * ys1; m[3] += w * (xs1 * xs1 + ys1 * ys1);
    m[4] += w * xs2; m[5] += w * ys2; m[6] += w * (xs2 * xs2 + ys2 * ys2);
    float a[9] = { xs1 * xs2, xs1 * ys2, xs1, ys1 * xs2, ys1 * ys2, ys1, xs2, ys2, 1.f };
    int idx = 7;
    #pragma unroll
    for (int u = 0; u < 9; ++u) {
        float wa = w * a[u];
        #pragma unroll
        for (int v = u; v < 9; ++v) { m[idx] = fmaf(wa, a[v], m[idx]); ++idx; }
    }
}

__device__ __forceinline__ void ph_moments(const float* __restrict__ Kmat,
        const float* __restrict__ tc, const int* __restrict__ rowcnt,
        const int* __restrict__ rowj, const float* __restrict__ roww,
        float* __restrict__ momp, int g, int t)
{
    int i = g * 256 + t;
    float ki0, ki1, ki2, ki3, ki4, ki5;
    kinv6(Kmat, ki0, ki1, ki2, ki3, ki4, ki5);
    float m[NMOM];
    #pragma unroll
    for (int k = 0; k < NMOM; ++k) m[k] = 0.f;
    int n = rowcnt[i]; n = n > 8 ? 8 : n;
    const int4*   jp = (const int4*)(rowj + (size_t)i * 8);
    const float4* vp = (const float4*)(roww + (size_t)i * 8);
    int4  ja = jp[0], jb = jp[1];
    float4 va = vp[0], vb = vp[1];
    float xg = (float)(i & 63) - 31.5f, yg = (float)(i >> 6) - 23.5f;
    float xs1 = ki0 * xg + ki1 * yg;
    float ys1 = ki3 * xg + ki4 * yg;
#define ACC(S, JR, VR) do { \
    if ((S) < n) { int _j = (JR); float _w = (VR); \
        if (_w >= tc[_j]) { \
            float _xg = (float)(_j & 63) - 31.5f, _yg = (float)(_j >> 6) - 23.5f; \
            float xs2 = ki0 * _xg + ki1 * _yg; \
            float ys2 = ki3 * _xg + ki4 * _yg; \
            acc_pair(m, _w, xs1, ys1, xs2, ys2); \
        } } } while (0)
    ACC(0, ja.x, va.x); ACC(1, ja.y, va.y); ACC(2, ja.z, va.z); ACC(3, ja.w, va.w);
    ACC(4, jb.x, vb.x); ACC(5, jb.y, vb.y); ACC(6, jb.z, vb.z); ACC(7, jb.w, vb.w);
#undef ACC
    #pragma unroll
    for (int k = 0; k < NMOM; ++k) {
        #pragma unroll
        for (int off = 32; off; off >>= 1) m[k] += __shfl_xor(m[k], off);
    }
    int lane = t & 63, wid = t >> 6;
    if (lane == 0) {
        float* dst = momp + (size_t)(g * 4 + wid) * 64;
        #pragma unroll
        for (int k = 0; k < NMOM; ++k) dst[k] = m[k];
    }
}

// ---------------- Phase 5: tail ---------------------------------------------
__device__ __forceinline__ void mm3r(const float* A, const float* B, float* C) {
    #pragma unroll
    for (int r = 0; r < 3; ++r)
        #pragma unroll
        for (int c = 0; c < 3; ++c)
            C[r * 3 + c] = A[r * 3 + 0] * B[0 + c] + A[r * 3 + 1] * B[3 + c] + A[r * 3 + 2] * B[6 + c];
}

__device__ __forceinline__ float det3(const float* M) {
    return M[0] * (M[4] * M[8] - M[5] * M[7])
         - M[1] * (M[3] * M[8] - M[5] * M[6])
         + M[2] * (M[3] * M[7] - M[4] * M[6]);
}

__device__ void ph_tail(const float* __restrict__ Kmat,
        const float* __restrict__ momp, float* __restrict__ out, int t)
{
    __shared__ float sMom[NMOM];
    __shared__ float sM[81], sY[81], sP[81], sT[81];
    __shared__ float sT1[9], sT2[9];

    if (t < NMOM) {
        float s = 0.f;
        #pragma unroll 8
        for (int b = 0; b < NPART; ++b) s += momp[(size_t)b * 64 + t];
        sMom[t] = s;
    }
    __syncthreads();

    float ki0, ki1, ki2, ki3, ki4, ki5;
    kinv6(Kmat, ki0, ki1, ki2, ki3, ki4, ki5);
    float u0x = ki0 * 31.5f + ki1 * 23.5f + ki2;
    float u0y = ki3 * 31.5f + ki4 * 23.5f + ki5;

    float Sw = sMom[0];
    float ws = Sw + EPSF;
    float c1x = sMom[1] / ws, c1y = sMom[2] / ws;
    float c2x = sMom[4] / ws, c2y = sMom[5] / ws;
    float q1 = (sMom[3] - 2.f * (c1x * sMom[1] + c1y * sMom[2]) + (c1x * c1x + c1y * c1y) * Sw) / ws;
    float q2 = (sMom[6] - 2.f * (c2x * sMom[4] + c2y * sMom[5]) + (c2x * c2x + c2y * c2y) * Sw) / ws;
    float md1 = sqrtf(fmaxf(q1, 0.f) + EPSF);
    float md2 = sqrtf(fmaxf(q2, 0.f) + EPSF);
    float s1 = 1.4142135623730951f / (md1 + EPSF);
    float s2 = 1.4142135623730951f / (md2 + EPSF);

    if (t < 81) {
        int r = t / 9, c = t % 9;
        int u = r < c ? r : c, v = r < c ? c : r;
        int idx = 7 + u * 9 - (u * (u + 1)) / 2 + v;
        sM[t] = sMom[idx];
    }
    if (t == 0) {
        sT1[0] = s1; sT1[1] = 0.f; sT1[2] = -s1 * c1x;
        sT1[3] = 0.f; sT1[4] = s1; sT1[5] = -s1 * c1y;
        sT1[6] = 0.f; sT1[7] = 0.f; sT1[8] = 1.f;
        sT2[0] = s2; sT2[1] = 0.f; sT2[2] = -s2 * c2x;
        sT2[3] = 0.f; sT2[4] = s2; sT2[5] = -s2 * c2y;
        sT2[6] = 0.f; sT2[7] = 0.f; sT2[8] = 1.f;
    }
    __syncthreads();

    if (t < 81) {
        int k = t / 9, c = t % 9;
        float s = 0.f;
        #pragma unroll
        for (int l = 0; l < 9; ++l)
            s = fmaf(sM[k * 9 + l], sT1[(c / 3) * 3 + (l / 3)] * sT2[(c % 3) * 3 + (l % 3)], s);
        sY[t] = s;
    }
    __syncthreads();
    if (t < 81) {
        int r = t / 9, c = t % 9;
        float s = 0.f;
        #pragma unroll
        for (int k = 0; k < 9; ++k)
            s = fmaf(sT1[(r / 3) * 3 + (k / 3)] * sT2[(r % 3) * 3 + (k % 3)], sY[k * 9 + c], s);
        sP[t] = s;
    }
    __syncthreads();
    if (t < 81) {
        int r = t / 9, c = t % 9;
        float lam = sP[0] + sP[10] + sP[20] + sP[30] + sP[40] + sP[50] + sP[60] + sP[70] + sP[80];
        float il = 1.f / (lam + 1e-30f);
        sM[t] = ((r == c ? lam : 0.f) - sP[t]) * il;
    }
    __syncthreads();

#define MM81(DST, A, B) \
    if (t < 81) { \
        int _r = t / 9, _c = t % 9; \
        float _s = 0.f; \
        _Pragma("unroll") \
        for (int _k = 0; _k < 9; ++_k) _s = fmaf(A[_r * 9 + _k], B[_k * 9 + _c], _s); \
        DST[t] = _s; \
    } \
    __syncthreads();

    MM81(sY, sM, sM)   // P2   (kept)
    MM81(sP, sY, sY)   // P4
    MM81(sT, sP, sP)   // P8
    MM81(sP, sT, sT)   // P16  (kept)
    MM81(sT, sP, sP)   // P32
    MM81(sM, sT, sP)   // R  = P32*P16
    MM81(sT, sM, sY)   // P50 = R*P2
#undef MM81

    if (t < 64) {
        float v9[9];
        float nrm = 0.f;
        #pragma unroll
        for (int r = 0; r < 9; ++r) {
            float s = 0.f;
            #pragma unroll
            for (int c = 0; c < 9; ++c) s += sT[r * 9 + c];
            v9[r] = s * (1.f / 3.f);
            nrm += v9[r] * v9[r];
        }
        nrm = sqrtf(nrm) + EPSF;
        #pragma unroll
        for (int r = 0; r < 9; ++r) v9[r] /= nrm;

        float C1x = c1x + u0x, C1y = c1y + u0y;
        float C2x = c2x + u0x, C2y = c2y + u0y;
        float T1f[9] = { s1, 0.f, -s1 * C1x, 0.f, s1, -s1 * C1y, 0.f, 0.f, 1.f };
        float T2t[9] = { s2, 0.f, 0.f, 0.f, s2, 0.f, -s2 * C2x, -s2 * C2y, 1.f };
        float M1[9], Ee[9];
        mm3r(v9, T1f, M1);
        mm3r(T2t, M1, Ee);

        float B[9];
        #pragma unroll
        for (int r = 0; r < 3; ++r)
            #pragma unroll
            for (int c = 0; c < 3; ++c)
                B[r * 3 + c] = Ee[r] * Ee[c] + Ee[3 + r] * Ee[3 + c] + Ee[6 + r] * Ee[6 + c];
        float lam3 = B[0] + B[4] + B[8];
        float il3 = 1.f / (lam3 + 1e-30f);

        int parity = t & 1;
        float P1[9];
        #pragma unroll
        for (int k = 0; k < 9; ++k) {
            float d = (k == 0 || k == 4 || k == 8) ? lam3 : 0.f;
            P1[k] = (parity ? (d - B[k]) : B[k]) * il3;
        }
        float P2[9], P4[9], P8[9], P16[9], P32[9], R1[9], P50[9];
        mm3r(P1, P1, P2);
        mm3r(P2, P2, P4);
        mm3r(P4, P4, P8);
        mm3r(P8, P8, P16);
        mm3r(P16, P16, P32);
        mm3r(P32, P16, R1);
        mm3r(R1, P2, P50);
        float vx = (P50[0] + P50[1] + P50[2]) * 0.57735026918962584f;
        float vy = (P50[3] + P50[4] + P50[5]) * 0.57735026918962584f;
        float vz = (P50[6] + P50[7] + P50[8]) * 0.57735026918962584f;
        float vn = sqrtf(vx * vx + vy * vy + vz * vz) + EPSF;
        vx /= vn; vy /= vn; vz /= vn;

        float v3x = __shfl(vx, 1), v3y = __shfl(vy, 1), v3z = __shfl(vz, 1);

        if (t == 0) {
            float v1[3] = { vx, vy, vz };
            float v3[3] = { v3x, v3y, v3z };
            float v2[3];
            v2[0] = v3[1] * v1[2] - v3[2] * v1[1];
            v2[1] = v3[2] * v1[0] - v3[0] * v1[2];
            v2[2] = v3[0] * v1[1] - v3[1] * v1[0];
            float n2 = sqrtf(v2[0] * v2[0] + v2[1] * v2[1] + v2[2] * v2[2]) + EPSF;
            v2[0] /= n2; v2[1] /= n2; v2[2] /= n2;
            float V[9];
            #pragma unroll
            for (int r = 0; r < 3; ++r) { V[r * 3 + 0] = v1[r]; V[r * 3 + 1] = v2[r]; V[r * 3 + 2] = v3[r]; }
            float dV = det3(V);
            float sV = (dV > 0.f) ? 1.f : ((dV < 0.f) ? -1.f : 0.f);
            V[2] *= sV; V[5] *= sV; V[8] *= sV;
            float Ev1[3], Ev2[3];
            #pragma unroll
            for (int r = 0; r < 3; ++r) {
                Ev1[r] = Ee[r * 3] * V[0] + Ee[r * 3 + 1] * V[3] + Ee[r * 3 + 2] * V[6];
                Ev2[r] = Ee[r * 3] * V[1] + Ee[r * 3 + 1] * V[4] + Ee[r * 3 + 2] * V[7];
            }
            float s1n = sqrtf(Ev1[0] * Ev1[0] + Ev1[1] * Ev1[1] + Ev1[2] * Ev1[2]);
            float s2n = sqrtf(Ev2[0] * Ev2[0] + Ev2[1] * Ev2[1] + Ev2[2] * Ev2[2]);
            float s_avg = (s1n + s2n) * 0.5f;
            float u1[3], u2[3];
            #pragma unroll
            for (int r = 0; r < 3; ++r) { u1[r] = Ev1[r] / (s1n + EPSF); u2[r] = Ev2[r] / (s2n + EPSF); }
            #pragma unroll
            for (int r = 0; r < 3; ++r)
                #pragma unroll
                for (int c = 0; c < 3; ++c)
                    out[r * 3 + c] = s_avg * (u1[r] * V[c * 3 + 0] + u2[r] * V[c * 3 + 1]);
        }
    }
}

// ================= Cooperative fused kernel (block-stride phases) ===========
__global__ __launch_bounds__(256, 3) void k_fused(const float* __restrict__ P,
        const float* __restrict__ Kmat, float* tr, float4* part, float* tc,
        int* rowcnt, int* rowj, float* roww, float* momp, float* out)
{
    cg::grid_group grid = cg::this_grid();
    int t = threadIdx.x;
    for (int g = blockIdx.x; g < NTILE_ROW; g += gridDim.x) ph_rowtop3(P, tr, rowcnt, g, t);
    grid.sync();
    for (int g = blockIdx.x; g < NTILE_COL; g += gridDim.x) ph_col(P, tr, part, rowcnt, rowj, roww, g, t);
    grid.sync();
    for (int g = blockIdx.x; g < NTILE_MRG; g += gridDim.x) ph_merge(part, tc, g, t);
    grid.sync();
    for (int g = blockIdx.x; g < NTILE_MOM; g += gridDim.x) ph_moments(Kmat, tc, rowcnt, rowj, roww, momp, g, t);
    grid.sync();
    if (blockIdx.x == 0) ph_tail(Kmat, momp, out, t);
}

// ================= Fallback separate kernels (R7-proven path) ===============
__global__ __launch_bounds__(256) void fb_row(const float* __restrict__ P,
        float* tr, int* rowcnt)
{ ph_rowtop3(P, tr, rowcnt, blockIdx.x, threadIdx.x); }

__global__ __launch_bounds__(256) void fb_col(const float* __restrict__ P,
        const float* __restrict__ tr, float4* part, int* rowcnt, int* rowj, float* roww)
{ ph_col(P, tr, part, rowcnt, rowj, roww, blockIdx.x, threadIdx.x); }

__global__ __launch_bounds__(256) void fb_merge(const float4* __restrict__ part, float* tc)
{ ph_merge(part, tc, blockIdx.x, threadIdx.x); }

__global__ __launch_bounds__(256) void fb_mom(const float* __restrict__ Kmat,
        const float* __restrict__ tc, const int* rowcnt, const int* rowj,
        const float* roww, float* momp)
{ ph_moments(Kmat, tc, rowcnt, rowj, roww, momp, blockIdx.x, threadIdx.x); }

__global__ __launch_bounds__(256) void fb_tail(const float* __restrict__ Kmat,
        const float* __restrict__ momp, float* out)
{ ph_tail(Kmat, momp, out, threadIdx.x); }

extern "C" void kernel_launch(void* const* d_in, const int* in_sizes, int n_in,
                              void* d_out, int out_size, void* d_ws, size_t ws_size,
                              hipStream_t stream)
{
    const float* P = (const float*)d_in[0];
    const float* K = (const float*)d_in[1];
    float* out = (float*)d_out;

    float* fws   = (float*)d_ws;
    float* tr    = fws;                          // NPV
    float* tc    = tr + NPV;                     // NPV
    float* roww  = tc + NPV;                     // 8N
    int*   rowj  = (int*)(roww + 8 * NPV);       // 8N
    int*   rowcnt = rowj + 8 * NPV;              // N
    float* momp  = (float*)(rowcnt + NPV);       // NPART*64
    float4* part = (float4*)(momp + NPART * 64); // NSEG*NPV float4 (offset 245760 B, 16B-aligned)

    bool coop_done = false;
    int nbPerCU = 0;
    hipError_t qe = hipOccupancyMaxActiveBlocksPerMultiprocessor(&nbPerCU, k_fused, 256, 0);
    if (qe == hipSuccess && nbPerCU > 0) {
        int numCU = 0;
        hipError_t ae = hipDeviceGetAttribute(&numCU, hipDeviceAttributeMultiprocessorCount, 0);
        if (ae != hipSuccess || numCU <= 0) numCU = 256;
        long long cap = (long long)nbPerCU * numCU;
        int grid = (int)(cap < NTILE_COL ? cap : NTILE_COL);
        void* args[] = { (void*)&P, (void*)&K, (void*)&tr, (void*)&part, (void*)&tc,
                         (void*)&rowcnt, (void*)&rowj, (void*)&roww, (void*)&momp, (void*)&out };
        hipError_t le = hipLaunchCooperativeKernel((const void*)k_fused, dim3(grid), dim3(256),
                                                   args, 0, stream);
        coop_done = (le == hipSuccess);
    }
    if (!coop_done) {
        fb_row  <<<NTILE_ROW, 256, 0, stream>>>(P, tr, rowcnt);
        fb_col  <<<NTILE_COL, 256, 0, stream>>>(P, tr, part, rowcnt, rowj, roww);
        fb_merge<<<NTILE_MRG, 256, 0, stream>>>(part, tc);
        fb_mom  <<<NTILE_MOM, 256, 0, stream>>>(K, tc, rowcnt, rowj, roww, momp);
        fb_tail <<<1, 256, 0, stream>>>(K, momp, out);
    }
}

// Round 11
// 44.522 us; speedup vs baseline: 6.3882x; 6.3882x over previous
//
#include <hip/hip_runtime.h>
#include <math.h>

#define NPV 3072
#define LDP 3073
#define EPSF 1e-8f
#define NMOM 52        // [0..6] w-moments, [7..51] 45-entry sym tensor
#define NSEG 64        // row segments (48 rows each)
#define NCHUNK 12      // column chunks (256 cols each)
#define NTILE (NSEG * NCHUNK)  // 768 tile blocks
#define NMOMBLK 12     // rowmom blocks
#define NPART (NMOMBLK * 4)    // 48 moment partials

// Branchless insert of v into sorted-descending value triple.
#define INS3(v, a, b, c) do { \
    float _m1 = fminf((a), (v)); (a) = fmaxf((a), (v)); \
    float _m2 = fminf((b), _m1); (b) = fmaxf((b), _m1); \
    (c) = fmaxf((c), _m2); } while (0)

#define MRG3(x, y, z, a, b, c) do { \
    INS3((x), a, b, c); INS3((y), a, b, c); INS3((z), a, b, c); } while (0)

// Branchless insert of (v,j) into descending (a,ja)>=(b,jb)>=(c,jc).
// Ties keep the incumbent (earlier-inserted = lower j when scanned ascending).
#define INSJ(v, j, a, ja, b, jb, c, jc) do { \
    bool _g1 = (v) > (a); \
    bool _g2 = (v) > (b); \
    bool _g3 = (v) > (c); \
    float _nc = _g2 ? (b) : (_g3 ? (v) : (c)); \
    int  _njc = _g2 ? (jb) : (_g3 ? (j) : (jc)); \
    float _nb = _g1 ? (a) : (_g2 ? (v) : (b)); \
    int  _njb = _g1 ? (ja) : (_g2 ? (j) : (jb)); \
    (a) = _g1 ? (v) : (a); \
    (ja) = _g1 ? (j) : (ja); \
    (b) = _nb; (jb) = _njb; \
    (c) = _nc; (jc) = _njc; } while (0)

__device__ __forceinline__ void kinv6(const float* __restrict__ Kmat,
        float& ki0, float& ki1, float& ki2, float& ki3, float& ki4, float& ki5)
{
    float k00 = Kmat[0], k01 = Kmat[1], k02 = Kmat[2];
    float k10 = Kmat[3], k11 = Kmat[4], k12 = Kmat[5];
    float k20 = Kmat[6], k21 = Kmat[7], k22 = Kmat[8];
    float det = k00 * (k11 * k22 - k12 * k21) - k01 * (k10 * k22 - k12 * k20) + k02 * (k10 * k21 - k11 * k20);
    float id = 1.0f / det;
    ki0 = (k11 * k22 - k12 * k21) * id; ki1 = (k02 * k21 - k01 * k22) * id; ki2 = (k01 * k12 - k02 * k11) * id;
    ki3 = (k12 * k20 - k10 * k22) * id; ki4 = (k00 * k22 - k02 * k20) * id; ki5 = (k02 * k10 - k00 * k12) * id;
}

// ======== Kernel 1: single pass over P. Col-top3 partials (registers) +
// row-top3-with-index per (row, chunk) via LDS tile. grid = 768 x 256. ======
__global__ __launch_bounds__(256) void k_tile(const float* __restrict__ P,
        float4* __restrict__ part, float* __restrict__ rpv, int* __restrict__ rpj)
{
    __shared__ float lds[48][257];
    int t = threadIdx.x;
    int chunk = blockIdx.x % NCHUNK;
    int seg   = blockIdx.x / NCHUNK;
    int j0 = chunk * 256;
    int i0 = seg * 48;
    const float* base = P + (size_t)i0 * LDP + j0 + t;

    float a0 = -1e30f, b0 = -1e30f, c0 = -1e30f;
    float a1 = -1e30f, b1 = -1e30f, c1 = -1e30f;
    float a2 = -1e30f, b2 = -1e30f, c2 = -1e30f;
    float a3 = -1e30f, b3 = -1e30f, c3 = -1e30f;
    float a4 = -1e30f, b4 = -1e30f, c4 = -1e30f;
    float a5 = -1e30f, b5 = -1e30f, c5 = -1e30f;
    float a6 = -1e30f, b6 = -1e30f, c6 = -1e30f;
    float a7 = -1e30f, b7 = -1e30f, c7 = -1e30f;
    #pragma unroll
    for (int r = 0; r < 48; r += 8) {
        float v0 = base[(size_t)(r + 0) * LDP];
        float v1 = base[(size_t)(r + 1) * LDP];
        float v2 = base[(size_t)(r + 2) * LDP];
        float v3 = base[(size_t)(r + 3) * LDP];
        float v4 = base[(size_t)(r + 4) * LDP];
        float v5 = base[(size_t)(r + 5) * LDP];
        float v6 = base[(size_t)(r + 6) * LDP];
        float v7 = base[(size_t)(r + 7) * LDP];
        lds[r + 0][t] = v0;
        lds[r + 1][t] = v1;
        lds[r + 2][t] = v2;
        lds[r + 3][t] = v3;
        lds[r + 4][t] = v4;
        lds[r + 5][t] = v5;
        lds[r + 6][t] = v6;
        lds[r + 7][t] = v7;
        INS3(v0, a0, b0, c0);
        INS3(v1, a1, b1, c1);
        INS3(v2, a2, b2, c2);
        INS3(v3, a3, b3, c3);
        INS3(v4, a4, b4, c4);
        INS3(v5, a5, b5, c5);
        INS3(v6, a6, b6, c6);
        INS3(v7, a7, b7, c7);
    }
    MRG3(a1, b1, c1, a0, b0, c0);
    MRG3(a2, b2, c2, a0, b0, c0);
    MRG3(a3, b3, c3, a0, b0, c0);
    MRG3(a4, b4, c4, a0, b0, c0);
    MRG3(a5, b5, c5, a0, b0, c0);
    MRG3(a6, b6, c6, a0, b0, c0);
    MRG3(a7, b7, c7, a0, b0, c0);
    part[(size_t)seg * NPV + j0 + t] = make_float4(a0, b0, c0, 0.f);

    __syncthreads();

    // Row phase: lane l (<48) owns tile-row l. 4 independent (v,j) triples.
    if (t < 48) {
        float A0 = -1e30f, B0 = -1e30f, C0 = -1e30f; int JA0 = 0, JB0 = 0, JC0 = 0;
        float A1 = -1e30f, B1 = -1e30f, C1 = -1e30f; int JA1 = 0, JB1 = 0, JC1 = 0;
        float A2 = -1e30f, B2 = -1e30f, C2 = -1e30f; int JA2 = 0, JB2 = 0, JC2 = 0;
        float A3 = -1e30f, B3 = -1e30f, C3 = -1e30f; int JA3 = 0, JB3 = 0, JC3 = 0;
        #pragma unroll 8
        for (int s = 0; s < 256; s += 4) {
            float v0 = lds[t][s + 0];
            float v1 = lds[t][s + 1];
            float v2 = lds[t][s + 2];
            float v3 = lds[t][s + 3];
            INSJ(v0, j0 + s + 0, A0, JA0, B0, JB0, C0, JC0);
            INSJ(v1, j0 + s + 1, A1, JA1, B1, JB1, C1, JC1);
            INSJ(v2, j0 + s + 2, A2, JA2, B2, JB2, C2, JC2);
            INSJ(v3, j0 + s + 3, A3, JA3, B3, JB3, C3, JC3);
        }
        INSJ(A1, JA1, A0, JA0, B0, JB0, C0, JC0);
        INSJ(B1, JB1, A0, JA0, B0, JB0, C0, JC0);
        INSJ(C1, JC1, A0, JA0, B0, JB0, C0, JC0);
        INSJ(A2, JA2, A0, JA0, B0, JB0, C0, JC0);
        INSJ(B2, JB2, A0, JA0, B0, JB0, C0, JC0);
        INSJ(C2, JC2, A0, JA0, B0, JB0, C0, JC0);
        INSJ(A3, JA3, A0, JA0, B0, JB0, C0, JC0);
        INSJ(B3, JB3, A0, JA0, B0, JB0, C0, JC0);
        INSJ(C3, JC3, A0, JA0, B0, JB0, C0, JC0);
        int i = i0 + t;
        rpv[(chunk * 3 + 0) * NPV + i] = A0;
        rpv[(chunk * 3 + 1) * NPV + i] = B0;
        rpv[(chunk * 3 + 2) * NPV + i] = C0;
        rpj[(chunk * 3 + 0) * NPV + i] = JA0;
        rpj[(chunk * 3 + 1) * NPV + i] = JB0;
        rpj[(chunk * 3 + 2) * NPV + i] = JC0;
    }
}

// ======== Kernel 2: merge col partials -> tc. Also zeroes the ticket. ======
__global__ __launch_bounds__(256) void k_colmerge(const float4* __restrict__ part,
        float* __restrict__ tc, int* __restrict__ ticket)
{
    if (blockIdx.x == 0 && threadIdx.x == 0) *ticket = 0;
    int sub = threadIdx.x & 15;
    int j = blockIdx.x * 16 + (threadIdx.x >> 4);
    float4 buf[NSEG / 16];
    #pragma unroll
    for (int k = 0; k < NSEG / 16; ++k)
        buf[k] = part[(size_t)(sub + (k << 4)) * NPV + j];
    float a = -1e30f, b = -1e30f, c = -1e30f;
    #pragma unroll
    for (int k = 0; k < NSEG / 16; ++k) MRG3(buf[k].x, buf[k].y, buf[k].z, a, b, c);
    #pragma unroll
    for (int off = 1; off < 16; off <<= 1) {
        float xa = __shfl_xor(a, off);
        float xb = __shfl_xor(b, off);
        float xc = __shfl_xor(c, off);
        MRG3(xa, xb, xc, a, b, c);
    }
    if (sub == 0) tc[j] = c;
}

// ---------------- moments + tail helpers ------------------------------------
__device__ __forceinline__ void acc_pair(float* m, float w, float xs1, float ys1,
                                         float xs2, float ys2)
{
    m[0] += w;
    m[1] += w * xs1; m[2] += w * ys1; m[3] += w * (xs1 * xs1 + ys1 * ys1);
    m[4] += w * xs2; m[5] += w * ys2; m[6] += w * (xs2 * xs2 + ys2 * ys2);
    float a[9] = { xs1 * xs2, xs1 * ys2, xs1, ys1 * xs2, ys1 * ys2, ys1, xs2, ys2, 1.f };
    int idx = 7;
    #pragma unroll
    for (int u = 0; u < 9; ++u) {
        float wa = w * a[u];
        #pragma unroll
        for (int v = u; v < 9; ++v) { m[idx] = fmaf(wa, a[v], m[idx]); ++idx; }
    }
}

__device__ __forceinline__ void mm3r(const float* A, const float* B, float* C) {
    #pragma unroll
    for (int r = 0; r < 3; ++r)
        #pragma unroll
        for (int c = 0; c < 3; ++c)
            C[r * 3 + c] = A[r * 3 + 0] * B[0 + c] + A[r * 3 + 1] * B[3 + c] + A[r * 3 + 2] * B[6 + c];
}

__device__ __forceinline__ float det3(const float* M) {
    return M[0] * (M[4] * M[8] - M[5] * M[7])
         - M[1] * (M[3] * M[8] - M[5] * M[6])
         + M[2] * (M[3] * M[7] - M[4] * M[6]);
}

__device__ void ph_tail(const float* __restrict__ Kmat,
        const float* __restrict__ momp, float* __restrict__ out, int t)
{
    __shared__ float sMom[NMOM];
    __shared__ float sM[81], sY[81], sP[81], sT[81];
    __shared__ float sT1[9], sT2[9];

    if (t < NMOM) {
        float s = 0.f;
        #pragma unroll 8
        for (int b = 0; b < NPART; ++b) s += momp[(size_t)b * 64 + t];
        sMom[t] = s;
    }
    __syncthreads();

    float ki0, ki1, ki2, ki3, ki4, ki5;
    kinv6(Kmat, ki0, ki1, ki2, ki3, ki4, ki5);
    float u0x = ki0 * 31.5f + ki1 * 23.5f + ki2;
    float u0y = ki3 * 31.5f + ki4 * 23.5f + ki5;

    float Sw = sMom[0];
    float ws = Sw + EPSF;
    float c1x = sMom[1] / ws, c1y = sMom[2] / ws;
    float c2x = sMom[4] / ws, c2y = sMom[5] / ws;
    float q1 = (sMom[3] - 2.f * (c1x * sMom[1] + c1y * sMom[2]) + (c1x * c1x + c1y * c1y) * Sw) / ws;
    float q2 = (sMom[6] - 2.f * (c2x * sMom[4] + c2y * sMom[5]) + (c2x * c2x + c2y * c2y) * Sw) / ws;
    float md1 = sqrtf(fmaxf(q1, 0.f) + EPSF);
    float md2 = sqrtf(fmaxf(q2, 0.f) + EPSF);
    float s1 = 1.4142135623730951f / (md1 + EPSF);
    float s2 = 1.4142135623730951f / (md2 + EPSF);

    if (t < 81) {
        int r = t / 9, c = t % 9;
        int u = r < c ? r : c, v = r < c ? c : r;
        int idx = 7 + u * 9 - (u * (u + 1)) / 2 + v;
        sM[t] = sMom[idx];
    }
    if (t == 0) {
        sT1[0] = s1; sT1[1] = 0.f; sT1[2] = -s1 * c1x;
        sT1[3] = 0.f; sT1[4] = s1; sT1[5] = -s1 * c1y;
        sT1[6] = 0.f; sT1[7] = 0.f; sT1[8] = 1.f;
        sT2[0] = s2; sT2[1] = 0.f; sT2[2] = -s2 * c2x;
        sT2[3] = 0.f; sT2[4] = s2; sT2[5] = -s2 * c2y;
        sT2[6] = 0.f; sT2[7] = 0.f; sT2[8] = 1.f;
    }
    __syncthreads();

    if (t < 81) {
        int k = t / 9, c = t % 9;
        float s = 0.f;
        #pragma unroll
        for (int l = 0; l < 9; ++l)
            s = fmaf(sM[k * 9 + l], sT1[(c / 3) * 3 + (l / 3)] * sT2[(c % 3) * 3 + (l % 3)], s);
        sY[t] = s;
    }
    __syncthreads();
    if (t < 81) {
        int r = t / 9, c = t % 9;
        float s = 0.f;
        #pragma unroll
        for (int k = 0; k < 9; ++k)
            s = fmaf(sT1[(r / 3) * 3 + (k / 3)] * sT2[(r % 3) * 3 + (k % 3)], sY[k * 9 + c], s);
        sP[t] = s;
    }
    __syncthreads();
    if (t < 81) {
        int r = t / 9, c = t % 9;
        float lam = sP[0] + sP[10] + sP[20] + sP[30] + sP[40] + sP[50] + sP[60] + sP[70] + sP[80];
        float il = 1.f / (lam + 1e-30f);
        sM[t] = ((r == c ? lam : 0.f) - sP[t]) * il;
    }
    __syncthreads();

#define MM81(DST, A, B) \
    if (t < 81) { \
        int _r = t / 9, _c = t % 9; \
        float _s = 0.f; \
        _Pragma("unroll") \
        for (int _k = 0; _k < 9; ++_k) _s = fmaf(A[_r * 9 + _k], B[_k * 9 + _c], _s); \
        DST[t] = _s; \
    } \
    __syncthreads();

    MM81(sY, sM, sM)   // P2   (kept)
    MM81(sP, sY, sY)   // P4
    MM81(sT, sP, sP)   // P8
    MM81(sP, sT, sT)   // P16  (kept)
    MM81(sT, sP, sP)   // P32
    MM81(sM, sT, sP)   // R  = P32*P16
    MM81(sT, sM, sY)   // P50 = R*P2
#undef MM81

    if (t < 64) {
        float v9[9];
        float nrm = 0.f;
        #pragma unroll
        for (int r = 0; r < 9; ++r) {
            float s = 0.f;
            #pragma unroll
            for (int c = 0; c < 9; ++c) s += sT[r * 9 + c];
            v9[r] = s * (1.f / 3.f);
            nrm += v9[r] * v9[r];
        }
        nrm = sqrtf(nrm) + EPSF;
        #pragma unroll
        for (int r = 0; r < 9; ++r) v9[r] /= nrm;

        float C1x = c1x + u0x, C1y = c1y + u0y;
        float C2x = c2x + u0x, C2y = c2y + u0y;
        float T1f[9] = { s1, 0.f, -s1 * C1x, 0.f, s1, -s1 * C1y, 0.f, 0.f, 1.f };
        float T2t[9] = { s2, 0.f, 0.f, 0.f, s2, 0.f, -s2 * C2x, -s2 * C2y, 1.f };
        float M1[9], Ee[9];
        mm3r(v9, T1f, M1);
        mm3r(T2t, M1, Ee);

        float B[9];
        #pragma unroll
        for (int r = 0; r < 3; ++r)
            #pragma unroll
            for (int c = 0; c < 3; ++c)
                B[r * 3 + c] = Ee[r] * Ee[c] + Ee[3 + r] * Ee[3 + c] + Ee[6 + r] * Ee[6 + c];
        float lam3 = B[0] + B[4] + B[8];
        float il3 = 1.f / (lam3 + 1e-30f);

        int parity = t & 1;
        float P1[9];
        #pragma unroll
        for (int k = 0; k < 9; ++k) {
            float d = (k == 0 || k == 4 || k == 8) ? lam3 : 0.f;
            P1[k] = (parity ? (d - B[k]) : B[k]) * il3;
        }
        float P2[9], P4[9], P8[9], P16[9], P32[9], R1[9], P50[9];
        mm3r(P1, P1, P2);
        mm3r(P2, P2, P4);
        mm3r(P4, P4, P8);
        mm3r(P8, P8, P16);
        mm3r(P16, P16, P32);
        mm3r(P32, P16, R1);
        mm3r(R1, P2, P50);
        float vx = (P50[0] + P50[1] + P50[2]) * 0.57735026918962584f;
        float vy = (P50[3] + P50[4] + P50[5]) * 0.57735026918962584f;
        float vz = (P50[6] + P50[7] + P50[8]) * 0.57735026918962584f;
        float vn = sqrtf(vx * vx + vy * vy + vz * vz) + EPSF;
        vx /= vn; vy /= vn; vz /= vn;

        float v3x = __shfl(vx, 1), v3y = __shfl(vy, 1), v3z = __shfl(vz, 1);

        if (t == 0) {
            float v1[3] = { vx, vy, vz };
            float v3[3] = { v3x, v3y, v3z };
            float v2[3];
            v2[0] = v3[1] * v1[2] - v3[2] * v1[1];
            v2[1] = v3[2] * v1[0] - v3[0] * v1[2];
            v2[2] = v3[0] * v1[1] - v3[1] * v1[0];
            float n2 = sqrtf(v2[0] * v2[0] + v2[1] * v2[1] + v2[2] * v2[2]) + EPSF;
            v2[0] /= n2; v2[1] /= n2; v2[2] /= n2;
            float V[9];
            #pragma unroll
            for (int r = 0; r < 3; ++r) { V[r * 3 + 0] = v1[r]; V[r * 3 + 1] = v2[r]; V[r * 3 + 2] = v3[r]; }
            float dV = det3(V);
            float sV = (dV > 0.f) ? 1.f : ((dV < 0.f) ? -1.f : 0.f);
            V[2] *= sV; V[5] *= sV; V[8] *= sV;
            float Ev1[3], Ev2[3];
            #pragma unroll
            for (int r = 0; r < 3; ++r) {
                Ev1[r] = Ee[r * 3] * V[0] + Ee[r * 3 + 1] * V[3] + Ee[r * 3 + 2] * V[6];
                Ev2[r] = Ee[r * 3] * V[1] + Ee[r * 3 + 1] * V[4] + Ee[r * 3 + 2] * V[7];
            }
            float s1n = sqrtf(Ev1[0] * Ev1[0] + Ev1[1] * Ev1[1] + Ev1[2] * Ev1[2]);
            float s2n = sqrtf(Ev2[0] * Ev2[0] + Ev2[1] * Ev2[1] + Ev2[2] * Ev2[2]);
            float s_avg = (s1n + s2n) * 0.5f;
            float u1[3], u2[3];
            #pragma unroll
            for (int r = 0; r < 3; ++r) { u1[r] = Ev1[r] / (s1n + EPSF); u2[r] = Ev2[r] / (s2n + EPSF); }
            #pragma unroll
            for (int r = 0; r < 3; ++r)
                #pragma unroll
                for (int c = 0; c < 3; ++c)
                    out[r * 3 + c] = s_avg * (u1[r] * V[c * 3 + 0] + u2[r] * V[c * 3 + 1]);
        }
    }
}

// ======== Kernel 3: merge row-chunk top-3s, filter, moments; last block
// (ticket, fence — no spin, deterministic) runs the tail. grid = 12 x 256. ==
__global__ __launch_bounds__(256) void k_rowmom(const float* __restrict__ Kmat,
        const float* __restrict__ tc, const float* __restrict__ rpv,
        const int* __restrict__ rpj, float* __restrict__ momp,
        int* __restrict__ ticket, float* __restrict__ out)
{
    __shared__ int slast;
    int t = threadIdx.x;
    int i = blockIdx.x * 256 + t;

    float A = -1e30f, B = -1e30f, C = -1e30f;
    int JA = 0, JB = 0, JC = 0;
    #pragma unroll
    for (int ch = 0; ch < NCHUNK; ++ch) {
        #pragma unroll
        for (int k = 0; k < 3; ++k) {
            float v = rpv[(size_t)(ch * 3 + k) * NPV + i];
            int   j = rpj[(size_t)(ch * 3 + k) * NPV + i];
            INSJ(v, j, A, JA, B, JB, C, JC);
        }
    }

    float ki0, ki1, ki2, ki3, ki4, ki5;
    kinv6(Kmat, ki0, ki1, ki2, ki3, ki4, ki5);
    float m[NMOM];
    #pragma unroll
    for (int k = 0; k < NMOM; ++k) m[k] = 0.f;
    float xg = (float)(i & 63) - 31.5f, yg = (float)(i >> 6) - 23.5f;
    float xs1 = ki0 * xg + ki1 * yg;
    float ys1 = ki3 * xg + ki4 * yg;
#define ACCJ(V, J) do { \
    if ((V) > 0.01f && (V) >= tc[J]) { \
        float _xg = (float)((J) & 63) - 31.5f, _yg = (float)((J) >> 6) - 23.5f; \
        float xs2 = ki0 * _xg + ki1 * _yg; \
        float ys2 = ki3 * _xg + ki4 * _yg; \
        acc_pair(m, (V), xs1, ys1, xs2, ys2); \
    } } while (0)
    ACCJ(A, JA);
    ACCJ(B, JB);
    ACCJ(C, JC);
#undef ACCJ

    #pragma unroll
    for (int k = 0; k < NMOM; ++k) {
        #pragma unroll
        for (int off = 32; off; off >>= 1) m[k] += __shfl_xor(m[k], off);
    }
    int lane = t & 63, wid = t >> 6;
    if (lane == 0) {
        float* dst = momp + (size_t)(blockIdx.x * 4 + wid) * 64;
        #pragma unroll
        for (int k = 0; k < NMOM; ++k) dst[k] = m[k];
    }

    // Last-ticket block runs the tail (all partials device-visible by then).
    __threadfence();
    __syncthreads();
    if (t == 0) slast = (atomicAdd(ticket, 1) == NMOMBLK - 1) ? 1 : 0;
    __syncthreads();
    if (!slast) return;
    __threadfence();
    ph_tail(Kmat, momp, out, t);
}

extern "C" void kernel_launch(void* const* d_in, const int* in_sizes, int n_in,
                              void* d_out, int out_size, void* d_ws, size_t ws_size,
                              hipStream_t stream)
{
    const float* P = (const float*)d_in[0];
    const float* K = (const float*)d_in[1];
    float* out = (float*)d_out;

    float* fws   = (float*)d_ws;
    float* tc    = fws;                            // 3072
    float* rpv   = tc + NPV;                       // 36*3072
    int*   rpj   = (int*)(rpv + 36 * NPV);         // 36*3072
    float* momp  = (float*)(rpj + 36 * NPV);       // 48*64
    int*   ticket = (int*)(momp + NPART * 64);     // 16 ints pad
    float4* part = (float4*)(ticket + 16);         // 64*3072 float4 (offset 909376 B, 16B-aligned)

    k_tile    <<<NTILE, 256, 0, stream>>>(P, part, rpv, rpj);
    k_colmerge<<<NPV / 16, 256, 0, stream>>>(part, tc, ticket);
    k_rowmom  <<<NMOMBLK, 256, 0, stream>>>(K, tc, rpv, rpj, momp, ticket, out);
}

// Round 12
// 40.106 us; speedup vs baseline: 7.0916x; 1.1101x over previous
//
#include <hip/hip_runtime.h>
#include <math.h>

#define NPV 3072
#define LDP 3073
#define EPSF 1e-8f
#define NMOM 52        // [0..6] w-moments, [7..51] 45-entry sym tensor
#define NSEG 64        // row segments (48 rows each)
#define NCHUNK 12      // column chunks (256 cols each)
#define NTILE (NSEG * NCHUNK)  // 768 tile blocks
#define NMOMBLK 12     // rowmom blocks
#define NPART (NMOMBLK * 4)    // 48 moment partials

// Branchless insert of v into sorted-descending value triple.
#define INS3(v, a, b, c) do { \
    float _m1 = fminf((a), (v)); (a) = fmaxf((a), (v)); \
    float _m2 = fminf((b), _m1); (b) = fmaxf((b), _m1); \
    (c) = fmaxf((c), _m2); } while (0)

#define MRG3(x, y, z, a, b, c) do { \
    INS3((x), a, b, c); INS3((y), a, b, c); INS3((z), a, b, c); } while (0)

// Branchless insert of (v,j) into descending (a,ja)>=(b,jb)>=(c,jc).
#define INSJ(v, j, a, ja, b, jb, c, jc) do { \
    bool _g1 = (v) > (a); \
    bool _g2 = (v) > (b); \
    bool _g3 = (v) > (c); \
    float _nc = _g2 ? (b) : (_g3 ? (v) : (c)); \
    int  _njc = _g2 ? (jb) : (_g3 ? (j) : (jc)); \
    float _nb = _g1 ? (a) : (_g2 ? (v) : (b)); \
    int  _njb = _g1 ? (ja) : (_g2 ? (j) : (jb)); \
    (a) = _g1 ? (v) : (a); \
    (ja) = _g1 ? (j) : (ja); \
    (b) = _nb; (jb) = _njb; \
    (c) = _nc; (jc) = _njc; } while (0)

__device__ __forceinline__ void kinv6(const float* __restrict__ Kmat,
        float& ki0, float& ki1, float& ki2, float& ki3, float& ki4, float& ki5)
{
    float k00 = Kmat[0], k01 = Kmat[1], k02 = Kmat[2];
    float k10 = Kmat[3], k11 = Kmat[4], k12 = Kmat[5];
    float k20 = Kmat[6], k21 = Kmat[7], k22 = Kmat[8];
    float det = k00 * (k11 * k22 - k12 * k21) - k01 * (k10 * k22 - k12 * k20) + k02 * (k10 * k21 - k11 * k20);
    float id = 1.0f / det;
    ki0 = (k11 * k22 - k12 * k21) * id; ki1 = (k02 * k21 - k01 * k22) * id; ki2 = (k01 * k12 - k02 * k11) * id;
    ki3 = (k12 * k20 - k10 * k22) * id; ki4 = (k00 * k22 - k02 * k20) * id; ki5 = (k02 * k10 - k00 * k12) * id;
}

// ======== Kernel 1: single pass over P. Col-top3 partials (registers) +
// row-top3-with-index per (row, chunk) via LDS tile. grid = 768 x 256. ======
__global__ __launch_bounds__(256) void k_tile(const float* __restrict__ P,
        float4* __restrict__ part, float* __restrict__ rpv, int* __restrict__ rpj)
{
    __shared__ float lds[48][257];
    int t = threadIdx.x;
    int chunk = blockIdx.x % NCHUNK;
    int seg   = blockIdx.x / NCHUNK;
    int j0 = chunk * 256;
    int i0 = seg * 48;
    const float* base = P + (size_t)i0 * LDP + j0 + t;

    float a0 = -1e30f, b0 = -1e30f, c0 = -1e30f;
    float a1 = -1e30f, b1 = -1e30f, c1 = -1e30f;
    float a2 = -1e30f, b2 = -1e30f, c2 = -1e30f;
    float a3 = -1e30f, b3 = -1e30f, c3 = -1e30f;
    float a4 = -1e30f, b4 = -1e30f, c4 = -1e30f;
    float a5 = -1e30f, b5 = -1e30f, c5 = -1e30f;
    float a6 = -1e30f, b6 = -1e30f, c6 = -1e30f;
    float a7 = -1e30f, b7 = -1e30f, c7 = -1e30f;
    #pragma unroll
    for (int r = 0; r < 48; r += 8) {
        float v0 = base[(size_t)(r + 0) * LDP];
        float v1 = base[(size_t)(r + 1) * LDP];
        float v2 = base[(size_t)(r + 2) * LDP];
        float v3 = base[(size_t)(r + 3) * LDP];
        float v4 = base[(size_t)(r + 4) * LDP];
        float v5 = base[(size_t)(r + 5) * LDP];
        float v6 = base[(size_t)(r + 6) * LDP];
        float v7 = base[(size_t)(r + 7) * LDP];
        lds[r + 0][t] = v0;
        lds[r + 1][t] = v1;
        lds[r + 2][t] = v2;
        lds[r + 3][t] = v3;
        lds[r + 4][t] = v4;
        lds[r + 5][t] = v5;
        lds[r + 6][t] = v6;
        lds[r + 7][t] = v7;
        INS3(v0, a0, b0, c0);
        INS3(v1, a1, b1, c1);
        INS3(v2, a2, b2, c2);
        INS3(v3, a3, b3, c3);
        INS3(v4, a4, b4, c4);
        INS3(v5, a5, b5, c5);
        INS3(v6, a6, b6, c6);
        INS3(v7, a7, b7, c7);
    }
    MRG3(a1, b1, c1, a0, b0, c0);
    MRG3(a2, b2, c2, a0, b0, c0);
    MRG3(a3, b3, c3, a0, b0, c0);
    MRG3(a4, b4, c4, a0, b0, c0);
    MRG3(a5, b5, c5, a0, b0, c0);
    MRG3(a6, b6, c6, a0, b0, c0);
    MRG3(a7, b7, c7, a0, b0, c0);
    part[(size_t)seg * NPV + j0 + t] = make_float4(a0, b0, c0, 0.f);

    __syncthreads();

    // Row phase: thread = row*4 + sub; each scans a 64-col subsegment with two
    // interleaved 32-deep (v,j) triples; shfl butterfly merges the 4 subs.
    if (t < 192) {
        int row = t >> 2, sub = t & 3;
        int cbase = sub * 64;
        int rot = (sub & 1) * 16;   // stagger scan start: banks {row, row+16} -> 2-way, free
        float A0 = -1e30f, B0 = -1e30f, C0 = -1e30f; int JA0 = 0, JB0 = 0, JC0 = 0;
        float A1 = -1e30f, B1 = -1e30f, C1 = -1e30f; int JA1 = 0, JB1 = 0, JC1 = 0;
        #pragma unroll 4
        for (int s = 0; s < 32; ++s) {
            int ia = (s + rot) & 31;
            int ib = 32 + ia;
            float va = lds[row][cbase + ia];
            float vb = lds[row][cbase + ib];
            INSJ(va, j0 + cbase + ia, A0, JA0, B0, JB0, C0, JC0);
            INSJ(vb, j0 + cbase + ib, A1, JA1, B1, JB1, C1, JC1);
        }
        INSJ(A1, JA1, A0, JA0, B0, JB0, C0, JC0);
        INSJ(B1, JB1, A0, JA0, B0, JB0, C0, JC0);
        INSJ(C1, JC1, A0, JA0, B0, JB0, C0, JC0);
        #pragma unroll
        for (int off = 1; off <= 2; off <<= 1) {
            float xa = __shfl_xor(A0, off);
            float xb = __shfl_xor(B0, off);
            float xc = __shfl_xor(C0, off);
            int   ya = __shfl_xor(JA0, off);
            int   yb = __shfl_xor(JB0, off);
            int   yc = __shfl_xor(JC0, off);
            INSJ(xa, ya, A0, JA0, B0, JB0, C0, JC0);
            INSJ(xb, yb, A0, JA0, B0, JB0, C0, JC0);
            INSJ(xc, yc, A0, JA0, B0, JB0, C0, JC0);
        }
        if (sub == 0) {
            int i = i0 + row;
            rpv[(size_t)(chunk * 3 + 0) * NPV + i] = A0;
            rpv[(size_t)(chunk * 3 + 1) * NPV + i] = B0;
            rpv[(size_t)(chunk * 3 + 2) * NPV + i] = C0;
            rpj[(size_t)(chunk * 3 + 0) * NPV + i] = JA0;
            rpj[(size_t)(chunk * 3 + 1) * NPV + i] = JB0;
            rpj[(size_t)(chunk * 3 + 2) * NPV + i] = JC0;
        }
    }
}

// ======== Kernel 2: merge col partials -> tc. Also zeroes the ticket. ======
__global__ __launch_bounds__(256) void k_colmerge(const float4* __restrict__ part,
        float* __restrict__ tc, int* __restrict__ ticket)
{
    if (blockIdx.x == 0 && threadIdx.x == 0) *ticket = 0;
    int sub = threadIdx.x & 15;
    int j = blockIdx.x * 16 + (threadIdx.x >> 4);
    float4 buf[NSEG / 16];
    #pragma unroll
    for (int k = 0; k < NSEG / 16; ++k)
        buf[k] = part[(size_t)(sub + (k << 4)) * NPV + j];
    float a = -1e30f, b = -1e30f, c = -1e30f;
    #pragma unroll
    for (int k = 0; k < NSEG / 16; ++k) MRG3(buf[k].x, buf[k].y, buf[k].z, a, b, c);
    #pragma unroll
    for (int off = 1; off < 16; off <<= 1) {
        float xa = __shfl_xor(a, off);
        float xb = __shfl_xor(b, off);
        float xc = __shfl_xor(c, off);
        MRG3(xa, xb, xc, a, b, c);
    }
    if (sub == 0) tc[j] = c;
}

// ---------------- moments + tail helpers ------------------------------------
__device__ __forceinline__ void acc_pair(float* m, float w, float xs1, float ys1,
                                         float xs2, float ys2)
{
    m[0] += w;
    m[1] += w * xs1; m[2] += w * ys1; m[3] += w * (xs1 * xs1 + ys1 * ys1);
    m[4] += w * xs2; m[5] += w * ys2; m[6] += w * (xs2 * xs2 + ys2 * ys2);
    float a[9] = { xs1 * xs2, xs1 * ys2, xs1, ys1 * xs2, ys1 * ys2, ys1, xs2, ys2, 1.f };
    int idx = 7;
    #pragma unroll
    for (int u = 0; u < 9; ++u) {
        float wa = w * a[u];
        #pragma unroll
        for (int v = u; v < 9; ++v) { m[idx] = fmaf(wa, a[v], m[idx]); ++idx; }
    }
}

__device__ __forceinline__ void mm3r(const float* A, const float* B, float* C) {
    #pragma unroll
    for (int r = 0; r < 3; ++r)
        #pragma unroll
        for (int c = 0; c < 3; ++c)
            C[r * 3 + c] = A[r * 3 + 0] * B[0 + c] + A[r * 3 + 1] * B[3 + c] + A[r * 3 + 2] * B[6 + c];
}

__device__ __forceinline__ float det3(const float* M) {
    return M[0] * (M[4] * M[8] - M[5] * M[7])
         - M[1] * (M[3] * M[8] - M[5] * M[6])
         + M[2] * (M[3] * M[7] - M[4] * M[6]);
}

__device__ void ph_tail(const float* __restrict__ Kmat,
        const float* __restrict__ momp, float* __restrict__ out, int t)
{
    __shared__ float sMom[NMOM];
    __shared__ float sM[81], sY[81], sP[81], sT[81];
    __shared__ float sT1[9], sT2[9];

    if (t < NMOM) {
        float s = 0.f;
        #pragma unroll 8
        for (int b = 0; b < NPART; ++b) s += momp[(size_t)b * 64 + t];
        sMom[t] = s;
    }
    __syncthreads();

    float ki0, ki1, ki2, ki3, ki4, ki5;
    kinv6(Kmat, ki0, ki1, ki2, ki3, ki4, ki5);
    float u0x = ki0 * 31.5f + ki1 * 23.5f + ki2;
    float u0y = ki3 * 31.5f + ki4 * 23.5f + ki5;

    float Sw = sMom[0];
    float ws = Sw + EPSF;
    float c1x = sMom[1] / ws, c1y = sMom[2] / ws;
    float c2x = sMom[4] / ws, c2y = sMom[5] / ws;
    float q1 = (sMom[3] - 2.f * (c1x * sMom[1] + c1y * sMom[2]) + (c1x * c1x + c1y * c1y) * Sw) / ws;
    float q2 = (sMom[6] - 2.f * (c2x * sMom[4] + c2y * sMom[5]) + (c2x * c2x + c2y * c2y) * Sw) / ws;
    float md1 = sqrtf(fmaxf(q1, 0.f) + EPSF);
    float md2 = sqrtf(fmaxf(q2, 0.f) + EPSF);
    float s1 = 1.4142135623730951f / (md1 + EPSF);
    float s2 = 1.4142135623730951f / (md2 + EPSF);

    if (t < 81) {
        int r = t / 9, c = t % 9;
        int u = r < c ? r : c, v = r < c ? c : r;
        int idx = 7 + u * 9 - (u * (u + 1)) / 2 + v;
        sM[t] = sMom[idx];
    }
    if (t == 0) {
        sT1[0] = s1; sT1[1] = 0.f; sT1[2] = -s1 * c1x;
        sT1[3] = 0.f; sT1[4] = s1; sT1[5] = -s1 * c1y;
        sT1[6] = 0.f; sT1[7] = 0.f; sT1[8] = 1.f;
        sT2[0] = s2; sT2[1] = 0.f; sT2[2] = -s2 * c2x;
        sT2[3] = 0.f; sT2[4] = s2; sT2[5] = -s2 * c2y;
        sT2[6] = 0.f; sT2[7] = 0.f; sT2[8] = 1.f;
    }
    __syncthreads();

    if (t < 81) {
        int k = t / 9, c = t % 9;
        float s = 0.f;
        #pragma unroll
        for (int l = 0; l < 9; ++l)
            s = fmaf(sM[k * 9 + l], sT1[(c / 3) * 3 + (l / 3)] * sT2[(c % 3) * 3 + (l % 3)], s);
        sY[t] = s;
    }
    __syncthreads();
    if (t < 81) {
        int r = t / 9, c = t % 9;
        float s = 0.f;
        #pragma unroll
        for (int k = 0; k < 9; ++k)
            s = fmaf(sT1[(r / 3) * 3 + (k / 3)] * sT2[(r % 3) * 3 + (k % 3)], sY[k * 9 + c], s);
        sP[t] = s;
    }
    __syncthreads();
    if (t < 81) {
        int r = t / 9, c = t % 9;
        float lam = sP[0] + sP[10] + sP[20] + sP[30] + sP[40] + sP[50] + sP[60] + sP[70] + sP[80];
        float il = 1.f / (lam + 1e-30f);
        sM[t] = ((r == c ? lam : 0.f) - sP[t]) * il;
    }
    __syncthreads();

#define MM81(DST, A, B) \
    if (t < 81) { \
        int _r = t / 9, _c = t % 9; \
        float _s = 0.f; \
        _Pragma("unroll") \
        for (int _k = 0; _k < 9; ++_k) _s = fmaf(A[_r * 9 + _k], B[_k * 9 + _c], _s); \
        DST[t] = _s; \
    } \
    __syncthreads();

    MM81(sY, sM, sM)   // P2   (kept)
    MM81(sP, sY, sY)   // P4
    MM81(sT, sP, sP)   // P8
    MM81(sP, sT, sT)   // P16  (kept)
    MM81(sT, sP, sP)   // P32
    MM81(sM, sT, sP)   // R  = P32*P16
    MM81(sT, sM, sY)   // P50 = R*P2
#undef MM81

    if (t < 64) {
        float v9[9];
        float nrm = 0.f;
        #pragma unroll
        for (int r = 0; r < 9; ++r) {
            float s = 0.f;
            #pragma unroll
            for (int c = 0; c < 9; ++c) s += sT[r * 9 + c];
            v9[r] = s * (1.f / 3.f);
            nrm += v9[r] * v9[r];
        }
        nrm = sqrtf(nrm) + EPSF;
        #pragma unroll
        for (int r = 0; r < 9; ++r) v9[r] /= nrm;

        float C1x = c1x + u0x, C1y = c1y + u0y;
        float C2x = c2x + u0x, C2y = c2y + u0y;
        float T1f[9] = { s1, 0.f, -s1 * C1x, 0.f, s1, -s1 * C1y, 0.f, 0.f, 1.f };
        float T2t[9] = { s2, 0.f, 0.f, 0.f, s2, 0.f, -s2 * C2x, -s2 * C2y, 1.f };
        float M1[9], Ee[9];
        mm3r(v9, T1f, M1);
        mm3r(T2t, M1, Ee);

        float B[9];
        #pragma unroll
        for (int r = 0; r < 3; ++r)
            #pragma unroll
            for (int c = 0; c < 3; ++c)
                B[r * 3 + c] = Ee[r] * Ee[c] + Ee[3 + r] * Ee[3 + c] + Ee[6 + r] * Ee[6 + c];
        float lam3 = B[0] + B[4] + B[8];
        float il3 = 1.f / (lam3 + 1e-30f);

        int parity = t & 1;
        float P1[9];
        #pragma unroll
        for (int k = 0; k < 9; ++k) {
            float d = (k == 0 || k == 4 || k == 8) ? lam3 : 0.f;
            P1[k] = (parity ? (d - B[k]) : B[k]) * il3;
        }
        float P2[9], P4[9], P8[9], P16[9], P32[9], R1[9], P50[9];
        mm3r(P1, P1, P2);
        mm3r(P2, P2, P4);
        mm3r(P4, P4, P8);
        mm3r(P8, P8, P16);
        mm3r(P16, P16, P32);
        mm3r(P32, P16, R1);
        mm3r(R1, P2, P50);
        float vx = (P50[0] + P50[1] + P50[2]) * 0.57735026918962584f;
        float vy = (P50[3] + P50[4] + P50[5]) * 0.57735026918962584f;
        float vz = (P50[6] + P50[7] + P50[8]) * 0.57735026918962584f;
        float vn = sqrtf(vx * vx + vy * vy + vz * vz) + EPSF;
        vx /= vn; vy /= vn; vz /= vn;

        float v3x = __shfl(vx, 1), v3y = __shfl(vy, 1), v3z = __shfl(vz, 1);

        if (t == 0) {
            float v1[3] = { vx, vy, vz };
            float v3[3] = { v3x, v3y, v3z };
            float v2[3];
            v2[0] = v3[1] * v1[2] - v3[2] * v1[1];
            v2[1] = v3[2] * v1[0] - v3[0] * v1[2];
            v2[2] = v3[0] * v1[1] - v3[1] * v1[0];
            float n2 = sqrtf(v2[0] * v2[0] + v2[1] * v2[1] + v2[2] * v2[2]) + EPSF;
            v2[0] /= n2; v2[1] /= n2; v2[2] /= n2;
            float V[9];
            #pragma unroll
            for (int r = 0; r < 3; ++r) { V[r * 3 + 0] = v1[r]; V[r * 3 + 1] = v2[r]; V[r * 3 + 2] = v3[r]; }
            float dV = det3(V);
            float sV = (dV > 0.f) ? 1.f : ((dV < 0.f) ? -1.f : 0.f);
            V[2] *= sV; V[5] *= sV; V[8] *= sV;
            float Ev1[3], Ev2[3];
            #pragma unroll
            for (int r = 0; r < 3; ++r) {
                Ev1[r] = Ee[r * 3] * V[0] + Ee[r * 3 + 1] * V[3] + Ee[r * 3 + 2] * V[6];
                Ev2[r] = Ee[r * 3] * V[1] + Ee[r * 3 + 1] * V[4] + Ee[r * 3 + 2] * V[7];
            }
            float s1n = sqrtf(Ev1[0] * Ev1[0] + Ev1[1] * Ev1[1] + Ev1[2] * Ev1[2]);
            float s2n = sqrtf(Ev2[0] * Ev2[0] + Ev2[1] * Ev2[1] + Ev2[2] * Ev2[2]);
            float s_avg = (s1n + s2n) * 0.5f;
            float u1[3], u2[3];
            #pragma unroll
            for (int r = 0; r < 3; ++r) { u1[r] = Ev1[r] / (s1n + EPSF); u2[r] = Ev2[r] / (s2n + EPSF); }
            #pragma unroll
            for (int r = 0; r < 3; ++r)
                #pragma unroll
                for (int c = 0; c < 3; ++c)
                    out[r * 3 + c] = s_avg * (u1[r] * V[c * 3 + 0] + u2[r] * V[c * 3 + 1]);
        }
    }
}

// ======== Kernel 3: merge row-chunk top-3s, filter, moments; last block
// (ticket, fence) runs the tail. grid = 12 x 256. =============================
__global__ __launch_bounds__(256) void k_rowmom(const float* __restrict__ Kmat,
        const float* __restrict__ tc, const float* __restrict__ rpv,
        const int* __restrict__ rpj, float* __restrict__ momp,
        int* __restrict__ ticket, float* __restrict__ out)
{
    __shared__ int slast;
    int t = threadIdx.x;
    int i = blockIdx.x * 256 + t;

    float A = -1e30f, B = -1e30f, C = -1e30f;
    int JA = 0, JB = 0, JC = 0;
    #pragma unroll
    for (int ch = 0; ch < NCHUNK; ++ch) {
        #pragma unroll
        for (int k = 0; k < 3; ++k) {
            float v = rpv[(size_t)(ch * 3 + k) * NPV + i];
            int   j = rpj[(size_t)(ch * 3 + k) * NPV + i];
            INSJ(v, j, A, JA, B, JB, C, JC);
        }
    }

    // Sort the 3 candidates ascending-j (matches jnp summation order).
#define CSWJ(jx, vx, jy, vy) do { \
        bool _sw = (jx) > (jy); \
        float _tv = _sw ? (vx) : (vy); \
        int   _tj = _sw ? (jx) : (jy); \
        (vx) = _sw ? (vy) : (vx); (jx) = _sw ? (jy) : (jx); \
        (vy) = _tv; (jy) = _tj; } while (0)
    CSWJ(JA, A, JB, B);
    CSWJ(JB, B, JC, C);
    CSWJ(JA, A, JB, B);
#undef CSWJ

    float ki0, ki1, ki2, ki3, ki4, ki5;
    kinv6(Kmat, ki0, ki1, ki2, ki3, ki4, ki5);
    float m[NMOM];
    #pragma unroll
    for (int k = 0; k < NMOM; ++k) m[k] = 0.f;
    float xg = (float)(i & 63) - 31.5f, yg = (float)(i >> 6) - 23.5f;
    float xs1 = ki0 * xg + ki1 * yg;
    float ys1 = ki3 * xg + ki4 * yg;
#define ACCJ(V, J) do { \
    if ((V) > 0.01f && (V) >= tc[J]) { \
        float _xg = (float)((J) & 63) - 31.5f, _yg = (float)((J) >> 6) - 23.5f; \
        float xs2 = ki0 * _xg + ki1 * _yg; \
        float ys2 = ki3 * _xg + ki4 * _yg; \
        acc_pair(m, (V), xs1, ys1, xs2, ys2); \
    } } while (0)
    ACCJ(A, JA);
    ACCJ(B, JB);
    ACCJ(C, JC);
#undef ACCJ

    #pragma unroll
    for (int k = 0; k < NMOM; ++k) {
        #pragma unroll
        for (int off = 32; off; off >>= 1) m[k] += __shfl_xor(m[k], off);
    }
    int lane = t & 63, wid = t >> 6;
    if (lane == 0) {
        float* dst = momp + (size_t)(blockIdx.x * 4 + wid) * 64;
        #pragma unroll
        for (int k = 0; k < NMOM; ++k) dst[k] = m[k];
    }

    __threadfence();
    __syncthreads();
    if (t == 0) slast = (atomicAdd(ticket, 1) == NMOMBLK - 1) ? 1 : 0;
    __syncthreads();
    if (!slast) return;
    __threadfence();
    ph_tail(Kmat, momp, out, t);
}

extern "C" void kernel_launch(void* const* d_in, const int* in_sizes, int n_in,
                              void* d_out, int out_size, void* d_ws, size_t ws_size,
                              hipStream_t stream)
{
    const float* P = (const float*)d_in[0];
    const float* K = (const float*)d_in[1];
    float* out = (float*)d_out;

    float* fws   = (float*)d_ws;
    float* tc    = fws;                            // 3072
    float* rpv   = tc + NPV;                       // 36*3072
    int*   rpj   = (int*)(rpv + 36 * NPV);         // 36*3072
    float* momp  = (float*)(rpj + 36 * NPV);       // 48*64
    int*   ticket = (int*)(momp + NPART * 64);     // 16 ints pad
    float4* part = (float4*)(ticket + 16);         // 64*3072 float4

    k_tile    <<<NTILE, 256, 0, stream>>>(P, part, rpv, rpj);
    k_colmerge<<<NPV / 16, 256, 0, stream>>>(part, tc, ticket);
    k_rowmom  <<<NMOMBLK, 256, 0, stream>>>(K, tc, rpv, rpj, momp, ticket, out);
}